// Round 2
// baseline (7750.906 us; speedup 1.0000x reference)
//
#include <hip/hip_runtime.h>
#include <hip/hip_bf16.h>

typedef unsigned short u16;
typedef __attribute__((ext_vector_type(8))) short shortx8;
typedef __attribute__((ext_vector_type(4))) float floatx4;
typedef __attribute__((ext_vector_type(4))) unsigned short ushortx4;

#define B_  32
#define S_  64
#define H_  2400
#define G3_ 7200
#define V_  20000
#define E_  300
#define EP_ 320
#define M_  2048   // B_*S_

// ---------- bf16 helpers (bit-level, avoids hip_bf16 type/version quirks) ----------
__device__ __forceinline__ u16 f32_to_bf16_rne(float f) {
  unsigned u = __float_as_uint(f);
  unsigned r = u + 0x7fffu + ((u >> 16) & 1u);
  return (u16)(r >> 16);
}
__device__ __forceinline__ float bf16_to_f32(u16 h) {
  return __uint_as_float(((unsigned)h) << 16);
}
__device__ __forceinline__ void split_bf16(float x, u16& h, u16& l) {
  h = f32_to_bf16_rne(x);
  float rem = x - bf16_to_f32(h);
  l = f32_to_bf16_rne(rem);
}

__device__ __forceinline__ void gl_lds16(const void* g, void* l) {
  __builtin_amdgcn_global_load_lds((const __attribute__((address_space(1))) void*)g,
                                   (__attribute__((address_space(3))) void*)l, 16, 0, 0);
}

// ---------- f32 -> bf16 hi/lo conversion, with column padding (zeros) ----------
__global__ __launch_bounds__(256) void convert_hilo(
    const float* __restrict__ src, int C, int Cp,
    u16* __restrict__ hi, u16* __restrict__ lo) {
  int r = blockIdx.y;
  int c = (blockIdx.x * 256 + threadIdx.x) * 4;
  if (c >= Cp) return;
  float x0, x1, x2, x3;
  if (c + 4 <= C) {
    float4 v = *reinterpret_cast<const float4*>(&src[(size_t)r * C + c]);
    x0 = v.x; x1 = v.y; x2 = v.z; x3 = v.w;
  } else {
    x0 = (c + 0 < C) ? src[(size_t)r * C + c + 0] : 0.f;
    x1 = (c + 1 < C) ? src[(size_t)r * C + c + 1] : 0.f;
    x2 = (c + 2 < C) ? src[(size_t)r * C + c + 2] : 0.f;
    x3 = (c + 3 < C) ? src[(size_t)r * C + c + 3] : 0.f;
  }
  u16 h0,h1,h2,h3,l0,l1,l2,l3;
  split_bf16(x0,h0,l0); split_bf16(x1,h1,l1);
  split_bf16(x2,h2,l2); split_bf16(x3,h3,l3);
  ushortx4 hv = { h0, h1, h2, h3 };
  ushortx4 lv = { l0, l1, l2, l3 };
  *reinterpret_cast<ushortx4*>(&hi[(size_t)r * Cp + c]) = hv;
  *reinterpret_cast<ushortx4*>(&lo[(size_t)r * Cp + c]) = lv;
}

// ---------- bf16x3 MFMA GEMM: C[m][n] = sum_k A[m][k]*B[n][k] + bias[n] ----------
// A given as hi/lo bf16 [M][K] (optionally row-gathered via gidx), B as hi/lo [N][K].
// 128x128 tile, BK=32, 4 waves, each wave 64x64 (4x4 frags of 16x16x32).
template<bool GATHER>
__global__ __launch_bounds__(256) void gemm3_bf16x3(
    const u16* __restrict__ Ah, const u16* __restrict__ Al,
    const u16* __restrict__ Bh, const u16* __restrict__ Bl,
    const int* __restrict__ gidx,
    const float* __restrict__ bias,
    float* __restrict__ Cc,
    int M, int N, int K) {
  __shared__ __align__(16) u16 sAh[128 * 32];
  __shared__ __align__(16) u16 sAl[128 * 32];
  __shared__ __align__(16) u16 sBh[128 * 32];
  __shared__ __align__(16) u16 sBl[128 * 32];

  const int t = threadIdx.x;
  const int lane = t & 63;
  const int w = t >> 6, wm = w >> 1, wn = w & 1;
  const int m0 = blockIdx.y * 128, n0 = blockIdx.x * 128;

  // staging: thread t covers row t/4 (+64 on 2nd issue), 8 bf16 at col (t%4)*8
  const int rl = t >> 2;
  const int c8 = (t & 3) * 8;
  size_t aoff0, aoff1;
  {
    int r0 = m0 + rl, r1 = m0 + rl + 64;
    if (GATHER) { r0 = gidx[r0]; r1 = gidx[r1]; }
    aoff0 = (size_t)r0 * K + c8;
    aoff1 = (size_t)r1 * K + c8;
  }
  int nr0 = n0 + rl;       if (nr0 > N - 1) nr0 = N - 1;
  int nr1 = n0 + rl + 64;  if (nr1 > N - 1) nr1 = N - 1;
  size_t boff0 = (size_t)nr0 * K + c8;
  size_t boff1 = (size_t)nr1 * K + c8;

  floatx4 acc[4][4] = {};

  for (int k0 = 0; k0 < K; k0 += 32) {
    __syncthreads();   // previous compute done before overwrite
    gl_lds16(&Ah[aoff0 + k0], (char*)sAh + t * 16);
    gl_lds16(&Ah[aoff1 + k0], (char*)sAh + t * 16 + 4096);
    gl_lds16(&Al[aoff0 + k0], (char*)sAl + t * 16);
    gl_lds16(&Al[aoff1 + k0], (char*)sAl + t * 16 + 4096);
    gl_lds16(&Bh[boff0 + k0], (char*)sBh + t * 16);
    gl_lds16(&Bh[boff1 + k0], (char*)sBh + t * 16 + 4096);
    gl_lds16(&Bl[boff0 + k0], (char*)sBl + t * 16);
    gl_lds16(&Bl[boff1 + k0], (char*)sBl + t * 16 + 4096);
    __syncthreads();   // compiler drains vmcnt before barrier

    const int ar = lane & 15, ak = (lane >> 4) * 8;
    shortx8 fah[4], fal[4], fbh[4], fbl[4];
#pragma unroll
    for (int i = 0; i < 4; ++i) {
      int arow = wm * 64 + i * 16 + ar;
      int brow = wn * 64 + i * 16 + ar;
      fah[i] = *reinterpret_cast<const shortx8*>((const char*)sAh + arow * 64 + ak * 2);
      fal[i] = *reinterpret_cast<const shortx8*>((const char*)sAl + arow * 64 + ak * 2);
      fbh[i] = *reinterpret_cast<const shortx8*>((const char*)sBh + brow * 64 + ak * 2);
      fbl[i] = *reinterpret_cast<const shortx8*>((const char*)sBl + brow * 64 + ak * 2);
    }
#pragma unroll
    for (int mi = 0; mi < 4; ++mi)
#pragma unroll
      for (int ni = 0; ni < 4; ++ni) {
        acc[mi][ni] = __builtin_amdgcn_mfma_f32_16x16x32_bf16(fah[mi], fbh[ni], acc[mi][ni], 0, 0, 0);
        acc[mi][ni] = __builtin_amdgcn_mfma_f32_16x16x32_bf16(fah[mi], fbl[ni], acc[mi][ni], 0, 0, 0);
        acc[mi][ni] = __builtin_amdgcn_mfma_f32_16x16x32_bf16(fal[mi], fbh[ni], acc[mi][ni], 0, 0, 0);
      }
  }

  // epilogue: C/D layout col=lane&15, row=(lane>>4)*4+reg  [m89]
#pragma unroll
  for (int mi = 0; mi < 4; ++mi)
#pragma unroll
    for (int ni = 0; ni < 4; ++ni) {
      int col = n0 + wn * 64 + ni * 16 + (lane & 15);
      if (col < N) {
        float bv = bias[col];
        int rowb = m0 + wm * 64 + mi * 16 + (lane >> 4) * 4;
#pragma unroll
        for (int r = 0; r < 4; ++r)
          Cc[(size_t)(rowb + r) * N + col] = acc[mi][ni][r] + bv;
      }
    }
}

// ---------- GRU step: fused hg GEMM (32 x 7200 x 2400 slice) + gates + h_new ----------
// grid 300 blocks (j-tiles of 8), 256 threads: thread = (jl 0..7, b 0..31),
// one (batch, j) pair per thread, all 3 gates.
__device__ __forceinline__ void gru_epi(
    int b, int s, int j, float ar, float az, float an,
    const float* __restrict__ hprev, int hstride,
    const float* __restrict__ xg, const float* __restrict__ bhh,
    float* __restrict__ hsf, u16* __restrict__ Ahi, u16* __restrict__ Alo) {
  int m = b * S_ + s;
  size_t xb = (size_t)m * G3_;
  float xr = xg[xb + j], xz = xg[xb + H_ + j], xn = xg[xb + 2 * H_ + j];
  float hr = ar + bhh[j], hz = az + bhh[H_ + j], hn = an + bhh[2 * H_ + j];
  float r = 1.f / (1.f + __expf(-(xr + hr)));
  float z = 1.f / (1.f + __expf(-(xz + hz)));
  float n = tanhf(xn + r * hn);
  float hold = hprev[(size_t)b * hstride + j];
  float hnew = (1.f - z) * n + z * hold;
  hsf[(size_t)m * H_ + j] = hnew;
  if (Ahi) {
    u16 hh, ll; split_bf16(hnew, hh, ll);
    Ahi[(size_t)m * H_ + j] = hh;
    Alo[(size_t)m * H_ + j] = ll;
  }
}

__global__ __launch_bounds__(256) void gru_step(
    const float* __restrict__ hprev, int hstride,
    const float* __restrict__ xg, int s,
    const float* __restrict__ Whh, const float* __restrict__ bhh,
    float* __restrict__ hsf, u16* __restrict__ Ahi, u16* __restrict__ Alo) {
  __shared__ __align__(16) float As[32 * 84];   // h rows, stride 84 (conflict pad)
  __shared__ __align__(16) float Wsh[24 * 84];  // 8 j x {r,z,n} rows
  const int t = threadIdx.x;
  const int jl = t & 7, b = t >> 3;             // b 0..31
  const int j0 = blockIdx.x * 8;
  const int j = j0 + jl;
  float ar = 0.f, az = 0.f, an = 0.f;
  const float* ap  = &As[b * 84];
  const float* wrp = &Wsh[jl * 84];
  const float* wzp = &Wsh[(8 + jl) * 84];
  const float* wnp = &Wsh[(16 + jl) * 84];

  for (int k0 = 0; k0 < H_; k0 += 80) {
    __syncthreads();
    for (int i = t; i < 1120; i += 256) {
      if (i < 640) {            // h: 32 rows x 20 float4
        int row = i / 20, c4 = (i % 20) * 4;
        *reinterpret_cast<float4*>(&As[row * 84 + c4]) =
            *reinterpret_cast<const float4*>(&hprev[(size_t)row * hstride + k0 + c4]);
      } else {                  // W_hh: 24 rows x 20 float4
        int ii = i - 640;
        int lr = ii / 20, c4 = (ii % 20) * 4;
        int gate = lr >> 3, jw = lr & 7;
        *reinterpret_cast<float4*>(&Wsh[lr * 84 + c4]) =
            *reinterpret_cast<const float4*>(&Whh[(size_t)(gate * H_ + j0 + jw) * H_ + k0 + c4]);
      }
    }
    __syncthreads();
#pragma unroll 5
    for (int kk = 0; kk < 80; kk += 4) {
      float4 a   = *reinterpret_cast<const float4*>(ap + kk);
      float4 wr4 = *reinterpret_cast<const float4*>(wrp + kk);
      float4 wz4 = *reinterpret_cast<const float4*>(wzp + kk);
      float4 wn4 = *reinterpret_cast<const float4*>(wnp + kk);
      ar += a.x*wr4.x + a.y*wr4.y + a.z*wr4.z + a.w*wr4.w;
      az += a.x*wz4.x + a.y*wz4.y + a.z*wz4.z + a.w*wz4.w;
      an += a.x*wn4.x + a.y*wn4.y + a.z*wn4.z + a.w*wn4.w;
    }
  }
  gru_epi(b, s, j, ar, az, an, hprev, hstride, xg, bhh, hsf, Ahi, Alo);
}

// ---------- fp32 naive GEMM fallback (used only if workspace is too small) ----------
template<bool GATHER>
__global__ __launch_bounds__(256) void gemm_f32_naive(
    const float* __restrict__ A, const int* __restrict__ gidx, int lda,
    const float* __restrict__ Bm, const float* __restrict__ bias,
    float* __restrict__ C, int M, int N, int K) {
  int n = blockIdx.x * 16 + (threadIdx.x & 15);
  int m = blockIdx.y * 16 + (threadIdx.x >> 4);
  if (m >= M || n >= N) return;
  const float* arow = GATHER ? (A + (size_t)gidx[m] * lda) : (A + (size_t)m * lda);
  const float* brow = Bm + (size_t)n * K;
  float acc = 0.f;
  for (int k = 0; k < K; ++k) acc += arow[k] * brow[k];
  C[(size_t)m * N + n] = acc + bias[n];
}

// ---------- host ----------
extern "C" void kernel_launch(void* const* d_in, const int* in_sizes, int n_in,
                              void* d_out, int out_size, void* d_ws, size_t ws_size,
                              hipStream_t stream) {
  const int*   tgt  = (const int*)d_in[0];
  const float* sv   = (const float*)d_in[1];
  const float* emb  = (const float*)d_in[2];
  const float* Wih  = (const float*)d_in[3];
  const float* Whh  = (const float*)d_in[4];
  const float* bih  = (const float*)d_in[5];
  const float* bhh  = (const float*)d_in[6];
  const float* Wout = (const float*)d_in[7];
  const float* bout = (const float*)d_in[8];
  float* out = (float*)d_out;
  char* ws = (char*)d_ws;

  size_t off = 0;
  auto alloc = [&](size_t bytes) { size_t o = off; off += (bytes + 255) & ~(size_t)255; return o; };
  size_t o_xg    = alloc((size_t)M_ * G3_ * 4);
  size_t o_hsf   = alloc((size_t)M_ * H_ * 4);
  size_t o_Ahi   = alloc((size_t)M_ * H_ * 2);
  size_t o_Alo   = alloc((size_t)M_ * H_ * 2);
  size_t o_Ehi   = alloc((size_t)V_ * EP_ * 2);
  size_t o_Elo   = alloc((size_t)V_ * EP_ * 2);
  size_t o_WiHi  = alloc((size_t)G3_ * EP_ * 2);
  size_t o_WiLo  = alloc((size_t)G3_ * EP_ * 2);
  size_t o_WoHi  = alloc((size_t)V_ * H_ * 2);
  size_t o_WoLo  = alloc((size_t)V_ * H_ * 2);
  size_t total_needed = off;

  float* xg  = (float*)(ws + o_xg);
  float* hsf = (float*)(ws + o_hsf);

  bool full = (ws_size >= total_needed);

  if (full) {
    u16* Ahi  = (u16*)(ws + o_Ahi);
    u16* Alo  = (u16*)(ws + o_Alo);
    u16* Ehi  = (u16*)(ws + o_Ehi);
    u16* Elo  = (u16*)(ws + o_Elo);
    u16* WiHi = (u16*)(ws + o_WiHi);
    u16* WiLo = (u16*)(ws + o_WiLo);
    u16* WoHi = (u16*)(ws + o_WoHi);
    u16* WoLo = (u16*)(ws + o_WoLo);

    convert_hilo<<<dim3(1, V_),  256, 0, stream>>>(emb,  E_, EP_, Ehi,  Elo);
    convert_hilo<<<dim3(1, G3_), 256, 0, stream>>>(Wih,  E_, EP_, WiHi, WiLo);
    convert_hilo<<<dim3(3, V_),  256, 0, stream>>>(Wout, H_, H_,  WoHi, WoLo);

    // x_gates = emb[tgt] @ W_ih^T + b_ih   (M=2048, N=7200, K=320 padded)
    gemm3_bf16x3<true><<<dim3(57, 16), 256, 0, stream>>>(
        Ehi, Elo, WiHi, WiLo, tgt, bih, xg, M_, G3_, EP_);

    for (int s = 0; s < S_; ++s) {
      const float* hp = (s == 0) ? sv : (hsf + (size_t)(s - 1) * H_);
      int hstride = (s == 0) ? H_ : S_ * H_;
      gru_step<<<300, 256, 0, stream>>>(hp, hstride, xg, s, Whh, bhh, hsf, Ahi, Alo);
    }

    // out = hs @ W_out^T + b_out   (M=2048, N=20000, K=2400)
    gemm3_bf16x3<false><<<dim3(157, 16), 256, 0, stream>>>(
        Ahi, Alo, WoHi, WoLo, nullptr, bout, out, M_, V_, H_);
  } else {
    // fp32 fallback: needs only xg + hsf (~79 MB)
    gemm_f32_naive<true><<<dim3(G3_ / 16, M_ / 16), 256, 0, stream>>>(
        emb, tgt, E_, Wih, bih, xg, M_, G3_, E_);
    for (int s = 0; s < S_; ++s) {
      const float* hp = (s == 0) ? sv : (hsf + (size_t)(s - 1) * H_);
      int hstride = (s == 0) ? H_ : S_ * H_;
      gru_step<<<300, 256, 0, stream>>>(hp, hstride, xg, s, Whh, bhh, hsf, nullptr, nullptr);
    }
    gemm_f32_naive<false><<<dim3(V_ / 16, M_ / 16), 256, 0, stream>>>(
        hsf, nullptr, H_, Wout, bout, out, M_, V_, H_);
  }
}